// Round 3
// baseline (111.090 us; speedup 1.0000x reference)
//
#include <hip/hip_runtime.h>

// Cubic B-spline interpolation (SplineInter), 2D, m=1024x1024, PAD=2.
// coeffs (1028 x 1028) float32, flat-clamped gather per reference.
//
// R1: row-vectorized gathers (4x dwordx4 per point).
// R2: 2 points per thread, 8 hoisted row loads (MLP).  [109.7 us]
// R3: global counting sort — FAILED (scatter write-amp, 160 us scatter).
// R4: quad-row repack (1 copy + shifted weights): eval 45.6 us, but total
//     107 us — rocprof shows the harness re-poisons the FULL 256 MB ws
//     (fillBufferAligned, ~46 us) inside the timed loop. Workspace use has
//     a ~46 us fixed tax; eval itself is line-fill/latency bound
//     (VALUBusy 11%, HBM 21%, nothing saturated).
// R5: row-PHASE-replicated quad layout. 4 copies; copy p holds
//     float4(coeffs[4i+p..4i+p+3][c]). Eval picks p = r0&3 so the whole
//     4x4 stencil is ONE contiguous 64B region (4 aligned dwordx4,
//     ~1.75 lines/point vs 3.5). Shifted-weight trick gone; FMA count
//     halves. Repack writes 16.9 MB (~4 us, L3-resident).
//     Predicted: eval ~20-25 us, total ~82-88 us.

#define I1 1028
#define TOTAL (1028 * 1028)
#define NQI 257                        // quad-row groups per copy
#define COPY_ELEMS (NQI * I1)          // 264196 float4 per copy
#define NCOPIES 4
#define QTOT (NCOPIES * COPY_ELEMS)    // 1,056,784 float4 (~16.9 MB)

// 4-float vector with only 4-byte alignment guarantee (slow/fallback paths).
typedef float f4u __attribute__((ext_vector_type(4), aligned(4)));

__device__ __forceinline__ void basis4(float t, float w[4]) {
    float a = 1.0f - t;
    w[0] = a * a * a;                                // j=-1: (1-t)^3
    w[1] = (3.0f * t - 6.0f) * (t * t) + 4.0f;       // j=0
    float xi = t - 1.0f;
    w[2] = -(3.0f * xi + 6.0f) * (xi * xi) + 4.0f;   // j=1
    w[3] = t * t * t;                                // j=2
}

struct PointSetup {
    int base;        // flat index into padded grid (row-major, stride I1)
    int r0, c0;      // first stencil row/col in padded coords
    bool valid;
    bool qinterior;  // phase fast path legal
    float w0[4], w1[4];
};

__device__ __forceinline__ PointSetup setup_point(float px, float py) {
    PointSetup ps;
    float xn0 = px * 1024.0f - 0.5f;
    float xn1 = py * 1024.0f - 0.5f;

    ps.valid = (xn0 > -2.0f) && (xn0 < 1024.0f) &&
               (xn1 > -2.0f) && (xn1 < 1024.0f);

    float P0f = floorf(xn0);
    float P1f = floorf(xn1);
    int P0 = (int)P0f;
    int P1 = (int)P1f;
    float t0 = xn0 - P0f;
    float t1 = xn1 - P1f;

    basis4(t0, ps.w0);
    basis4(t1, ps.w1);

    ps.base = I1 * (2 + P0) + (2 + P1);
    ps.r0 = P0 + 1;   // first of 4 stencil rows (padded coords)
    ps.c0 = P1 + 1;   // first of 4 stencil cols
    // Fast path: rows r0..r0+3 and cols c0..c0+3 fully within [0,1027].
    // Then the reference's flat clamp can never fire, and copy (r0&3),
    // group (r0>>2) covers exactly rows r0..r0+3.
    ps.qinterior = (ps.r0 >= 0) && (ps.r0 <= 1024) &&
                   (ps.c0 >= 0) && (ps.c0 <= 1024);
    return ps;
}

__device__ __forceinline__ float eval_slow(const float* __restrict__ coeffs,
                                           const PointSetup& ps) {
    float acc = 0.0f;
#pragma unroll
    for (int j = 0; j < 4; ++j) {
        int r = ps.base + (j - 1) * I1 - 1;
        float s = 0.0f;
#pragma unroll
        for (int k = 0; k < 4; ++k) {
            int idx = r + k;
            idx = min(max(idx, 0), TOTAL - 1);  // flat clamp, matches jnp.clip
            s = fmaf(coeffs[idx], ps.w1[k], s);
        }
        acc = fmaf(s, ps.w0[j], acc);
    }
    return acc;
}

// Stencil reduce on phase layout: v[k] = float4 of rows r0..r0+3 at col c0+k.
__device__ __forceinline__ float reduce_phase(const float4 v[4], const PointSetup& ps) {
    float acc = 0.0f;
#pragma unroll
    for (int k = 0; k < 4; ++k) {
        float col = fmaf(v[k].x, ps.w0[0],
                    fmaf(v[k].y, ps.w0[1],
                    fmaf(v[k].z, ps.w0[2],
                         v[k].w * ps.w0[3])));
        acc = fmaf(col, ps.w1[k], acc);
    }
    return acc;
}

// ---------------- Phase repack (streaming pre-pass, ~16.9 MB write) --------

__global__ __launch_bounds__(256) void phasepack_kernel(
    const float* __restrict__ coeffs, float4* __restrict__ Q)
{
    int idx = blockIdx.x * blockDim.x + threadIdx.x;
    if (idx >= QTOT) return;
    int p   = idx / COPY_ELEMS;
    int rem = idx - p * COPY_ELEMS;
    int i   = rem / I1;
    int c   = rem - i * I1;
    int r   = 4 * i + p;
    // Rows past 1027 exist only in never-read blocks (fast path guarantees
    // 4i+p+3 <= 1027); clamp to stay in-bounds.
    int r0 = min(r,     1027);
    int r1 = min(r + 1, 1027);
    int r2 = min(r + 2, 1027);
    int r3 = min(r + 3, 1027);
    float4 v;
    v.x = coeffs[r0 * I1 + c];
    v.y = coeffs[r1 * I1 + c];
    v.z = coeffs[r2 * I1 + c];
    v.w = coeffs[r3 * I1 + c];
    Q[idx] = v;
}

// ---------------- Eval on phase layout ----------------

__global__ __launch_bounds__(256) void eval_phase_kernel(
    const float* __restrict__ x,      // [N,2] interleaved
    const float* __restrict__ coeffs, // original (slow path)
    const float4* __restrict__ Q,     // phase-replicated quad layout
    float* __restrict__ out, int n)
{
    int g = blockIdx.x * blockDim.x + threadIdx.x;
    int i0 = 2 * g;
    if (i0 >= n) return;

    if (i0 + 1 < n) {
        // Two consecutive points: one coalesced float4 x-load, float2 out-store.
        float4 two = reinterpret_cast<const float4*>(x)[g];
        PointSetup psA = setup_point(two.x, two.y);
        PointSetup psB = setup_point(two.z, two.w);

        float accA, accB;
        if (psA.qinterior && psB.qinterior) {
            const float4* qA = Q + (psA.r0 & 3) * COPY_ELEMS
                                 + (psA.r0 >> 2) * I1 + psA.c0;
            const float4* qB = Q + (psB.r0 & 3) * COPY_ELEMS
                                 + (psB.r0 >> 2) * I1 + psB.c0;
            // 2 points x 4 aligned dwordx4 from ONE 64B region each; all 8
            // loads hoisted for MLP.
            float4 vA[4], vB[4];
#pragma unroll
            for (int k = 0; k < 4; ++k) {
                vA[k] = qA[k];
                vB[k] = qB[k];
            }
            accA = reduce_phase(vA, psA);
            accB = reduce_phase(vB, psB);
        } else {
            accA = eval_slow(coeffs, psA);
            accB = eval_slow(coeffs, psB);
        }

        float2 o;
        o.x = psA.valid ? accA : 0.0f;
        o.y = psB.valid ? accB : 0.0f;
        reinterpret_cast<float2*>(out)[g] = o;
    } else {
        // odd tail point
        float px = x[2 * i0], py = x[2 * i0 + 1];
        PointSetup ps = setup_point(px, py);
        float acc = eval_slow(coeffs, ps);
        out[i0] = ps.valid ? acc : 0.0f;
    }
}

// ---------------- Fallback direct kernel (R2, proven) ----------------

__global__ __launch_bounds__(256) void spline_interp_kernel(
    const float* __restrict__ x,
    const float* __restrict__ coeffs,
    float* __restrict__ out,
    int n, int half)
{
    int i = blockIdx.x * blockDim.x + threadIdx.x;
    if (i >= half) return;
    int i2 = i + half;

    float2 xyA = reinterpret_cast<const float2*>(x)[i];
    float2 xyB = reinterpret_cast<const float2*>(x)[i2];

    PointSetup psA = setup_point(xyA.x, xyA.y);
    PointSetup psB = setup_point(xyB.x, xyB.y);

    float accA, accB;
    bool interiorA = (psA.base - I1 - 1 >= 0) && (psA.base + 2 * I1 + 2 <= TOTAL - 1);
    bool interiorB = (psB.base - I1 - 1 >= 0) && (psB.base + 2 * I1 + 2 <= TOTAL - 1);
    if (interiorA && interiorB) {
        f4u vA[4], vB[4];
#pragma unroll
        for (int j = 0; j < 4; ++j) {
            vA[j] = *reinterpret_cast<const f4u*>(coeffs + psA.base + (j - 1) * I1 - 1);
            vB[j] = *reinterpret_cast<const f4u*>(coeffs + psB.base + (j - 1) * I1 - 1);
        }
        float a0 = 0.0f, a1 = 0.0f;
#pragma unroll
        for (int j = 0; j < 4; ++j) {
            float s0 = fmaf(vA[j].x, psA.w1[0], fmaf(vA[j].y, psA.w1[1],
                       fmaf(vA[j].z, psA.w1[2], vA[j].w * psA.w1[3])));
            a0 = fmaf(s0, psA.w0[j], a0);
            float s1 = fmaf(vB[j].x, psB.w1[0], fmaf(vB[j].y, psB.w1[1],
                       fmaf(vB[j].z, psB.w1[2], vB[j].w * psB.w1[3])));
            a1 = fmaf(s1, psB.w0[j], a1);
        }
        accA = a0; accB = a1;
    } else {
        accA = eval_slow(coeffs, psA);
        accB = eval_slow(coeffs, psB);
    }

    out[i]  = psA.valid ? accA : 0.0f;
    out[i2] = psB.valid ? accB : 0.0f;
}

// ---------------- Launch ----------------

extern "C" void kernel_launch(void* const* d_in, const int* in_sizes, int n_in,
                              void* d_out, int out_size, void* d_ws, size_t ws_size,
                              hipStream_t stream) {
    const float* x = (const float*)d_in[0];       // [N,2]
    const float* coeffs = (const float*)d_in[1];  // [1028*1028]
    float* out = (float*)d_out;                   // [N]

    int n = in_sizes[0] / 2;   // number of points (2,097,152)

    size_t need = (size_t)QTOT * 16;   // 16.9 MB phase-replicated layout

    if (ws_size >= need) {
        float4* Q = (float4*)d_ws;

        int gpack = (QTOT + 255) / 256;
        phasepack_kernel<<<gpack, 256, 0, stream>>>(coeffs, Q);

        int pairs = (n + 1) / 2;
        int geval = (pairs + 255) / 256;
        eval_phase_kernel<<<geval, 256, 0, stream>>>(x, coeffs, Q, out, n);
    } else {
        // Fallback: proven R2 direct kernel
        int half = n / 2;
        int block = 256;
        int grid = (half + block - 1) / block;
        spline_interp_kernel<<<grid, block, 0, stream>>>(x, coeffs, out, n, half);
    }
}